// Round 10
// baseline (3734.476 us; speedup 1.0000x reference)
//
#include <hip/hip_runtime.h>
#include <math.h>

// Problem dims
#define B_   256
#define T_   512
#define F_   64
#define H1_  100
#define H2_  128
#define OUT_ 19
#define G1_  400   // 4*H1
#define G2_  512   // 4*H2
#define TC   32    // timesteps per chunk
#define NCHUNK (T_/TC)

typedef unsigned int uint;
typedef _Float16 h16;
typedef __attribute__((ext_vector_type(2))) _Float16 h16x2;

// ---- LDS layout (BYTE offsets), phase-overlaid ----
// xp1 fp32[32][400]   [0,51200)          A0 w -> A1 r
// xp2 fp16[32][512]   [0,32768)          A2 w -> B r       (overlays xp1)
// WQ  W1 8q*400*16    [51200,102400)     A0
//     U1 13q*400*16   [51200,134400)     A1                (overlays W1)
// XS  1024 u32        [134400,138496)    A0
// W2Q 13q*512*16      [32768,139264)     A2                (overlays U1/XS/xp1-tail)
// H1C 32t*208B        [139264,145920)    A1 w -> A2 r
// U2Q 15q*512*16      [32768,155648)     B                 (overlays W2Q, dead H1C)
// ZB0 fp32[512]       [155648,157696)    z ping
// ZB1 fp32[512]       [157696,159744)    z pong
// HP1 8w*208B         [159744,161408)    per-wave private h1 (PERSISTENT)
// HP2 8w*256B         [161408,163456)    per-wave private h2 (PERSISTENT)
#define OFF_XP1  0
#define OFF_XP2  0
#define OFF_WQ   51200
#define OFF_XS   134400
#define OFF_W2Q  32768
#define OFF_H1C  139264
#define OFF_U2Q  32768
#define OFF_ZB0  155648
#define OFF_ZB1  157696
#define OFF_HP1  159744
#define OFF_HP2  161408
#define LDS_BYTES 163456   // <= 163840

__device__ __forceinline__ float sigm(float x) {
    return 1.0f / (1.0f + __expf(-x));
}

__device__ __forceinline__ uint pk2(float a, float b) {
    h16x2 h; h.x = (h16)a; h.y = (h16)b;
    return __builtin_bit_cast(uint, h);
}

__device__ __forceinline__ float fd2(uint w, uint h, float c) {
#if __has_builtin(__builtin_amdgcn_fdot2)
    return __builtin_amdgcn_fdot2(__builtin_bit_cast(h16x2, w),
                                  __builtin_bit_cast(h16x2, h), c, false);
#else
    h16x2 a = __builtin_bit_cast(h16x2, w), b = __builtin_bit_cast(h16x2, h);
    return c + (float)a.x * (float)b.x + (float)a.y * (float)b.y;
#endif
}

#define FD4(w, p, s) fd2((w).w,(p).w, fd2((w).z,(p).z, fd2((w).y,(p).y, fd2((w).x,(p).x,(s)))))

// Stage fp32 P[K x G] into LDS fp16 quad-rows (zero-padded past KREAL).
__device__ __forceinline__ void stage_quads(const float* __restrict__ P, const int G,
                                            const int NQ, const int KREAL,
                                            char* dst, const int j)
{
    if (j < G) {
        for (int q = 0; q < NQ; ++q) {
            float f[8];
            #pragma unroll
            for (int r = 0; r < 8; ++r) {
                const int k = 8 * q + r;
                f[r] = (k < KREAL) ? P[(size_t)k * G + j] : 0.0f;
            }
            uint4 u;
            u.x = pk2(f[0], f[1]); u.y = pk2(f[2], f[3]);
            u.z = pk2(f[4], f[5]); u.w = pk2(f[6], f[7]);
            *(uint4*)(dst + (size_t)(q * G + j) * 16) = u;
        }
    }
}

#define A0R(i) { uint4 p = *(const uint4*)(sm + OFF_XS + (tb+i)*128 + q*16); s##i = FD4(w,p,s##i); }
#define A0W(i) *(float*)(sm + OFF_XP1 + 4*((tb+i)*G1_+j)) = s##i;
#define A2R(i) { uint4 p = *(const uint4*)(sm + OFF_H1C + (tb+i)*208 + q*16); s##i = FD4(w,p,s##i); }
#define A2W(i) *(h16*)(sm + OFF_XP2 + 2*((tb+i)*G2_+j)) = (h16)s##i;
#define R8(M) M(0) M(1) M(2) M(3) M(4) M(5) M(6) M(7)

__global__ __launch_bounds__(512)
void lstm_fused(
    const float* __restrict__ x,
    const float* __restrict__ W1, const float* __restrict__ U1, const float* __restrict__ b1,
    const float* __restrict__ W2, const float* __restrict__ U2, const float* __restrict__ b2,
    const float* __restrict__ Wd, const float* __restrict__ bd,
    float* __restrict__ out)
{
    __shared__ uint4 smem4[LDS_BYTES / 16];
    char* sm = (char*)smem4;
    const int b    = blockIdx.x;
    const int j    = threadIdx.x;
    const int wid  = j >> 6;
    const int lane = j & 63;

    // Replicated cell state (identical in every wave)
    float c1a = 0.f, c1b = 0.f, c2a = 0.f, c2b = 0.f;

    // U2 rows 120..127 (quad 15) as 4 named uints, loaded once
    const uint u2r0 = pk2(U2[120 * G2_ + j], U2[121 * G2_ + j]);
    const uint u2r1 = pk2(U2[122 * G2_ + j], U2[123 * G2_ + j]);
    const uint u2r2 = pk2(U2[124 * G2_ + j], U2[125 * G2_ + j]);
    const uint u2r3 = pk2(U2[126 * G2_ + j], U2[127 * G2_ + j]);

    // zero private h buffers (persist across chunks)
    if (j < 416) *(uint*)(sm + OFF_HP1 + 4 * j) = 0u;
    *(uint*)(sm + OFF_HP2 + 4 * j) = 0u;
    __syncthreads();

    const float* xrow = x + (size_t)b * T_ * F_;

    for (int ch = 0; ch < NCHUNK; ++ch) {
        // ---- stage W1 quads + x pairs ----
        stage_quads(W1, G1_, 8, 64, sm + OFF_WQ, j);
        #pragma unroll
        for (int r = 0; r < 2; ++r) {
            int v = r * 512 + j;
            float2 xv = *(const float2*)(xrow + ch * (TC * F_) + 2 * v);
            *(uint*)(sm + OFF_XS + 4 * v) = pk2(xv.x, xv.y);
        }
        __syncthreads();

        // ---- A0 (t-blocked x8): xp1 = b1 + x.W1 ----
        if (j < G1_) {
            const float bj = b1[j];
            for (int tb = 0; tb < TC; tb += 8) {
                float s0=bj,s1=bj,s2=bj,s3=bj,s4=bj,s5=bj,s6=bj,s7=bj;
                #pragma unroll
                for (int q = 0; q < 8; ++q) {
                    uint4 w = *(const uint4*)(sm + OFF_WQ + (size_t)(q*G1_+j)*16);
                    R8(A0R)
                }
                R8(A0W)
            }
        }
        __syncthreads();   // W1Q dead
        stage_quads(U1, G1_, 13, H1_, sm + OFF_WQ, j);
        __syncthreads();

        // ---- A1: layer-1 recurrence, ONE barrier/step ----
        for (int t = 0; t < TC; ++t) {
            const int zo = (t & 1) ? OFF_ZB1 : OFF_ZB0;
            if (j < G1_) {
                const char* hp = sm + OFF_HP1 + wid * 208;
                float a0 = *(const float*)(sm + OFF_XP1 + 4 * (t * G1_ + j));
                float a1 = 0.f, a2 = 0.f, a3 = 0.f;
                #pragma unroll
                for (int q = 0; q < 13; ++q) {
                    uint4 w = *(const uint4*)(sm + OFF_WQ + (size_t)(q*G1_+j)*16);
                    uint4 p = *(const uint4*)(hp + q * 16);
                    a0 = fd2(w.x,p.x,a0); a1 = fd2(w.y,p.y,a1);
                    a2 = fd2(w.z,p.z,a2); a3 = fd2(w.w,p.w,a3);
                }
                *(float*)(sm + zo + 4 * j) = (a0 + a1) + (a2 + a3);
            }
            __syncthreads();
            {   // replicated gates: every wave computes all units for its own copy
                const float* zb = (const float*)(sm + zo);
                char* hp = sm + OFF_HP1 + wid * 208;
                float ig = sigm(zb[lane]);
                float fg = sigm(zb[lane + 100]);
                float gg = fmaxf(zb[lane + 200], 0.f);
                float og = sigm(zb[lane + 300]);
                c1a = fg * c1a + ig * gg;
                float ha = og * fmaxf(c1a, 0.f);
                *(h16*)(hp + 2 * lane) = (h16)ha;
                if (wid == 0) *(h16*)(sm + OFF_H1C + t * 208 + 2 * lane) = (h16)ha;
                if (lane < 36) {
                    float ig2 = sigm(zb[lane + 64]);
                    float fg2 = sigm(zb[lane + 164]);
                    float gg2 = fmaxf(zb[lane + 264], 0.f);
                    float og2 = sigm(zb[lane + 364]);
                    c1b = fg2 * c1b + ig2 * gg2;
                    float hb = og2 * fmaxf(c1b, 0.f);
                    *(h16*)(hp + 2 * (lane + 64)) = (h16)hb;
                    if (wid == 0) *(h16*)(sm + OFF_H1C + t * 208 + 2 * (lane + 64)) = (h16)hb;
                }
            }
            // no second barrier: next dot reads own-wave private h (lgkmcnt-ordered)
        }

        // ---- stage W2 (region disjoint from gate buffers) ----
        stage_quads(W2, G2_, 13, H1_, sm + OFF_W2Q, j);
        __syncthreads();   // W2 staged + wave0's H1C writes visible

        // ---- A2 (t-blocked x8): xp2 = b2 + h1c.W2 ----
        {
            const float bj = b2[j];
            for (int tb = 0; tb < TC; tb += 8) {
                float s0=bj,s1=bj,s2=bj,s3=bj,s4=bj,s5=bj,s6=bj,s7=bj;
                #pragma unroll
                for (int q = 0; q < 13; ++q) {
                    uint4 w = *(const uint4*)(sm + OFF_W2Q + (size_t)(q*G2_+j)*16);
                    R8(A2R)
                }
                R8(A2W)
            }
        }
        __syncthreads();   // W2Q/H1C dead
        stage_quads(U2, G2_, 15, 120, sm + OFF_U2Q, j);
        __syncthreads();

        // ---- B: layer-2 recurrence, ONE barrier/step ----
        for (int t = 0; t < TC; ++t) {
            const int zo = (t & 1) ? OFF_ZB1 : OFF_ZB0;
            {
                const char* hp = sm + OFF_HP2 + wid * 256;
                float a0 = (float)*(const h16*)(sm + OFF_XP2 + 2 * (t * G2_ + j));
                float a1 = 0.f, a2 = 0.f, a3 = 0.f;
                #pragma unroll
                for (int q = 0; q < 15; ++q) {
                    uint4 w = *(const uint4*)(sm + OFF_U2Q + (size_t)(q*G2_+j)*16);
                    uint4 p = *(const uint4*)(hp + q * 16);
                    a0 = fd2(w.x,p.x,a0); a1 = fd2(w.y,p.y,a1);
                    a2 = fd2(w.z,p.z,a2); a3 = fd2(w.w,p.w,a3);
                }
                uint4 p15 = *(const uint4*)(hp + 240);
                a0 = fd2(u2r0, p15.x, a0); a1 = fd2(u2r1, p15.y, a1);
                a2 = fd2(u2r2, p15.z, a2); a3 = fd2(u2r3, p15.w, a3);
                *(float*)(sm + zo + 4 * j) = (a0 + a1) + (a2 + a3);
            }
            __syncthreads();
            {   // replicated gates, 2 units/lane (both valid)
                const float* zb = (const float*)(sm + zo);
                char* hp = sm + OFF_HP2 + wid * 256;
                float ig = sigm(zb[lane]);
                float fg = sigm(zb[lane + 128]);
                float gg = fmaxf(zb[lane + 256], 0.f);
                float og = sigm(zb[lane + 384]);
                c2a = fg * c2a + ig * gg;
                *(h16*)(hp + 2 * lane) = (h16)(og * fmaxf(c2a, 0.f));
                float ig2 = sigm(zb[lane + 64]);
                float fg2 = sigm(zb[lane + 192]);
                float gg2 = fmaxf(zb[lane + 320], 0.f);
                float og2 = sigm(zb[lane + 448]);
                c2b = fg2 * c2b + ig2 * gg2;
                *(h16*)(hp + 2 * (lane + 64)) = (h16)(og2 * fmaxf(c2b, 0.f));
            }
        }
    }

    // ---- head: logits = h2_last @ Wd + bd ; softmax over 19 ----
    __syncthreads();
    if (j < OUT_) {
        const char* hp0 = sm + OFF_HP2;   // wave 0's h2 copy
        float acc = bd[j];
        #pragma unroll
        for (int k = 0; k < H2_; ++k)
            acc += (float)*(const h16*)(hp0 + 2 * k) * Wd[k * OUT_ + j];
        *(float*)(sm + OFF_ZB0 + 4 * j) = acc;
    }
    __syncthreads();
    if (j < OUT_) {
        const float* zb = (const float*)(sm + OFF_ZB0);
        float m = -1e30f;
        for (int k = 0; k < OUT_; ++k) m = fmaxf(m, zb[k]);
        float s = 0.0f;
        for (int k = 0; k < OUT_; ++k) s += expf(zb[k] - m);
        out[b * OUT_ + j] = expf(zb[j] - m) / s;
    }
}

extern "C" void kernel_launch(void* const* d_in, const int* in_sizes, int n_in,
                              void* d_out, int out_size, void* d_ws, size_t ws_size,
                              hipStream_t stream) {
    const float* x  = (const float*)d_in[0];
    const float* W1 = (const float*)d_in[1];
    const float* U1 = (const float*)d_in[2];
    const float* b1 = (const float*)d_in[3];
    const float* W2 = (const float*)d_in[4];
    const float* U2 = (const float*)d_in[5];
    const float* b2 = (const float*)d_in[6];
    const float* Wd = (const float*)d_in[7];
    const float* bd = (const float*)d_in[8];
    float* out = (float*)d_out;

    hipLaunchKernelGGL(lstm_fused, dim3(B_), dim3(512), 0, stream,
                       x, W1, U1, b1, W2, U2, b2, Wd, bd, out);
}

// Round 11
// 1734.590 us; speedup vs baseline: 2.1529x; 2.1529x over previous
//
#include <hip/hip_runtime.h>
#include <math.h>

// Problem dims
#define B_   256
#define T_   512
#define F_   64
#define H1_  100
#define H2_  128
#define OUT_ 19
#define TCH  128            // timesteps per chunk (pipeline granularity)
#define NCH  (T_/TCH)       // 4 chunks
#define NPC  512            // padded+permuted gate columns (both layers)
#define KP   128            // padded K (units) for both layers

typedef unsigned int uint;
typedef _Float16 h16;
typedef __attribute__((ext_vector_type(2))) _Float16 h16x2;
typedef __attribute__((ext_vector_type(8))) _Float16 f16x8;
typedef __attribute__((ext_vector_type(4))) float f32x4;

// ---- workspace layout (bytes) ----
#define OFF_XP    0ull
#define XP_BYTES  (16ull*TCH*NPC*16*2)     // 33,554,432
#define OFF_H1G   (OFF_XP + XP_BYTES)
#define H1G_BYTES (16ull*TCH*KP*16*2)      // 8,388,608
#define OFF_C1    (OFF_H1G + H1G_BYTES)
#define CST_BYTES (16ull*KP*16*4)          // 131,072
#define OFF_C2    (OFF_C1 + CST_BYTES)
#define OFF_H1S   (OFF_C2 + CST_BYTES)
#define HST_BYTES (16ull*KP*16*2)          // 65,536
#define OFF_H2S   (OFF_H1S + HST_BYTES)
#define WS_NEED   (OFF_H2S + HST_BYTES)    // ~42.3 MB

__device__ __forceinline__ float sigm(float x) { return 1.0f / (1.0f + __expf(-x)); }

__device__ __forceinline__ uint pk2(float a, float b) {
    h16x2 h; h.x = (h16)a; h.y = (h16)b;
    return __builtin_bit_cast(uint, h);
}

__device__ __forceinline__ f32x4 mfma16(f16x8 a, f16x8 b, f32x4 c) {
    return __builtin_amdgcn_mfma_f32_16x16x32_f16(a, b, c, 0, 0, 0);
}

// unpack 4 f16 (uint2) -> f32x4
__device__ __forceinline__ f32x4 up4(uint2 v) {
    h16x2 a = __builtin_bit_cast(h16x2, v.x);
    h16x2 b = __builtin_bit_cast(h16x2, v.y);
    f32x4 r; r[0] = (float)a.x; r[1] = (float)a.y; r[2] = (float)b.x; r[3] = (float)b.y;
    return r;
}

// B-fragment loader with gate-column permutation.
// Permuted col c = w*64 + g*16 + ci  <->  unit u = w*16+ci, orig col = g*H + u.
// Fragment (MFMA 16x16x32 B): lane holds B[k = q*32 + (lane>>4)*8 + e][ci = lane&15].
__device__ __forceinline__ f16x8 load_bfrag(const float* __restrict__ P, int H, int OG,
                                            int Kreal, int w, int g, int q, int lane) {
    const int u  = w * 16 + (lane & 15);
    const int k0 = q * 32 + (lane >> 4) * 8;
    const int col = g * H + u;
    float f[8];
    #pragma unroll
    for (int e = 0; e < 8; ++e) {
        const int k = k0 + e;
        f[e] = (u < H && k < Kreal) ? P[(size_t)k * OG + col] : 0.0f;
    }
    uint4 r;
    r.x = pk2(f[0], f[1]); r.y = pk2(f[2], f[3]);
    r.z = pk2(f[4], f[5]); r.w = pk2(f[6], f[7]);
    return __builtin_bit_cast(f16x8, r);
}

// ================= dense pre-projection GEMM =================
// MODE 0: A = x (fp32), K=64 (Kreal 64), out xp1. MODE 1: A = h1g (f16), K=128 (Kreal 100), out xp2.
// Grid 128 blocks x 512 thr; block handles 16 M-tiles (16 batch rows x 1 t each).
template<int MODE>
__global__ __launch_bounds__(512) void k_dense(
    const float* __restrict__ Af, const h16* __restrict__ Ah,
    const float* __restrict__ W, const float* __restrict__ bias,
    const int H, const int ch, h16* __restrict__ xp)
{
    const int j = threadIdx.x, lane = j & 63, w = j >> 6;
    const int KF = MODE ? 4 : 2;
    const int KREAL = MODE ? 100 : 64;
    const int OG = 4 * H;

    f16x8 bf[4][4];
    #pragma unroll
    for (int g = 0; g < 4; ++g)
        #pragma unroll
        for (int q = 0; q < 4; ++q)
            if (q < KF) bf[g][q] = load_bfrag(W, H, OG, KREAL, w, g, q, lane);

    float bv[4];
    #pragma unroll
    for (int g = 0; g < 4; ++g) {
        const int u = w * 16 + (lane & 15);
        bv[g] = (u < H) ? bias[g * H + u] : 0.0f;
    }

    const int ci = lane & 15, hi = lane >> 4;
    for (int it = 0; it < 16; ++it) {
        const int m = blockIdx.x * 16 + it;
        const int bt = m >> 7, tc = m & 127;

        f16x8 af[4];
        if (MODE == 0) {
            const int b = bt * 16 + ci;
            const int t = ch * TCH + tc;
            #pragma unroll
            for (int q = 0; q < 2; ++q) {
                const int k0 = q * 32 + hi * 8;
                const float* p = Af + ((size_t)b * T_ + t) * F_ + k0;
                float4 x0 = *(const float4*)p;
                float4 x1 = *(const float4*)(p + 4);
                uint4 r;
                r.x = pk2(x0.x, x0.y); r.y = pk2(x0.z, x0.w);
                r.z = pk2(x1.x, x1.y); r.w = pk2(x1.z, x1.w);
                af[q] = __builtin_bit_cast(f16x8, r);
            }
        } else {
            #pragma unroll
            for (int q = 0; q < 4; ++q) {
                const int k0 = q * 32 + hi * 8;
                const size_t base = ((size_t)(bt * TCH + tc) * KP + k0) * 16 + ci;
                f16x8 a;
                #pragma unroll
                for (int e = 0; e < 8; ++e) a[e] = Ah[base + (size_t)e * 16];
                af[q] = a;
            }
        }

        f32x4 acc[4];
        #pragma unroll
        for (int g = 0; g < 4; ++g) { acc[g][0]=bv[g]; acc[g][1]=bv[g]; acc[g][2]=bv[g]; acc[g][3]=bv[g]; }
        #pragma unroll
        for (int g = 0; g < 4; ++g)
            #pragma unroll
            for (int q = 0; q < 4; ++q)
                if (q < KF) acc[g] = mfma16(af[q], bf[g][q], acc[g]);

        #pragma unroll
        for (int g = 0; g < 4; ++g) {
            const int c = (w * 4 + g) * 16 + ci;
            const size_t o = ((size_t)(bt * TCH + tc) * NPC + c) * 16 + hi * 4;
            uint2 s;
            s.x = pk2(acc[g][0], acc[g][1]);
            s.y = pk2(acc[g][2], acc[g][3]);
            *(uint2*)(xp + o) = s;
        }
    }
}

// ================= recurrence kernel =================
// 16 blocks x 512 thr. Weights live in VGPR fragments for the whole chunk.
#define LF(G,Q) f16x8 wf##G##Q = load_bfrag(U, H, 4*H, H, w, G, Q, lane); \
                asm volatile("" ::: "memory");

__global__ __launch_bounds__(512) void k_rec(
    const float* __restrict__ U, const int H,
    const h16* __restrict__ xp, h16* __restrict__ hout, const int do_hout,
    float* __restrict__ cstate, h16* __restrict__ hstate, const int ch)
{
    __shared__ h16 hbuf[2][16][136];   // [buf][batch-row][unit], 272B row stride
    const int j = threadIdx.x, lane = j & 63, w = j >> 6;
    const int bt = blockIdx.x;
    const int ci = lane & 15, hi = lane >> 4;
    const int myu = w * 16 + ci;
    const int r0 = hi * 4;

    LF(0,0) LF(0,1) LF(0,2) LF(0,3)
    LF(1,0) LF(1,1) LF(1,2) LF(1,3)
    LF(2,0) LF(2,1) LF(2,2) LF(2,3)
    LF(3,0) LF(3,1) LF(3,2) LF(3,3)

    // init hbuf[0] with carried h state (or zeros)
    {
        const int u = j & 127, rr = (j >> 7) * 4;
        #pragma unroll
        for (int i = 0; i < 4; ++i) {
            h16 v = (h16)0.0f;
            if (ch != 0) v = hstate[((size_t)bt * KP + u) * 16 + rr + i];
            hbuf[0][rr + i][u] = v;
        }
    }
    // carried c state
    f32x4 c;
    const size_t coff = ((size_t)bt * KP + myu) * 16 + r0;
    if (ch == 0) { c[0]=0.f; c[1]=0.f; c[2]=0.f; c[3]=0.f; }
    else         { c = *(const f32x4*)(cstate + coff); }
    __syncthreads();

    // xp addressing (h16-element offsets, fits uint)
    const uint xstep = NPC * 16;
    uint xb0 = (uint)(((size_t)bt * TCH) * NPC + (w * 64 + 0 * 16 + ci)) * 16 + r0;
    uint xb1 = xb0 + 16 * 16, xb2 = xb0 + 32 * 16, xb3 = xb0 + 48 * 16;
    uint2 xn0 = *(const uint2*)(xp + xb0);
    uint2 xn1 = *(const uint2*)(xp + xb1);
    uint2 xn2 = *(const uint2*)(xp + xb2);
    uint2 xn3 = *(const uint2*)(xp + xb3);

    const uint hstep = KP * 16;
    uint hob = (uint)(((size_t)bt * TCH) * KP + myu) * 16 + r0;

    uint2 hp; hp.x = 0u; hp.y = 0u;

    for (int t = 0; t < TCH; ++t) {
        const h16* hb = &hbuf[t & 1][0][0];
        // A-fragments: lane holds h[row=ci][k = q*32 + hi*8 + e]
        f16x8 a0 = *(const f16x8*)(hb + ci * 136 + 0  + hi * 8);
        f16x8 a1 = *(const f16x8*)(hb + ci * 136 + 32 + hi * 8);
        f16x8 a2 = *(const f16x8*)(hb + ci * 136 + 64 + hi * 8);
        f16x8 a3 = *(const f16x8*)(hb + ci * 136 + 96 + hi * 8);

        f32x4 z0 = up4(xn0), z1 = up4(xn1), z2 = up4(xn2), z3 = up4(xn3);

        // prefetch next step's xp
        const int tn = (t + 1 < TCH) ? t + 1 : t;
        xn0 = *(const uint2*)(xp + xb0 + (uint)tn * xstep);
        xn1 = *(const uint2*)(xp + xb1 + (uint)tn * xstep);
        xn2 = *(const uint2*)(xp + xb2 + (uint)tn * xstep);
        xn3 = *(const uint2*)(xp + xb3 + (uint)tn * xstep);

        z0 = mfma16(a0, wf00, z0); z0 = mfma16(a1, wf01, z0); z0 = mfma16(a2, wf02, z0); z0 = mfma16(a3, wf03, z0);
        z1 = mfma16(a0, wf10, z1); z1 = mfma16(a1, wf11, z1); z1 = mfma16(a2, wf12, z1); z1 = mfma16(a3, wf13, z1);
        z2 = mfma16(a0, wf20, z2); z2 = mfma16(a1, wf21, z2); z2 = mfma16(a2, wf22, z2); z2 = mfma16(a3, wf23, z2);
        z3 = mfma16(a0, wf30, z3); z3 = mfma16(a1, wf31, z3); z3 = mfma16(a2, wf32, z3); z3 = mfma16(a3, wf33, z3);

        f32x4 hv;
        #pragma unroll
        for (int i = 0; i < 4; ++i) {
            float ig = sigm(z0[i]);
            float fg = sigm(z1[i]);
            float gg = fmaxf(z2[i], 0.0f);
            float og = sigm(z3[i]);
            c[i] = fg * c[i] + ig * gg;
            hv[i] = og * fmaxf(c[i], 0.0f);
        }
        h16 h0 = (h16)hv[0], h1 = (h16)hv[1], h2 = (h16)hv[2], h3 = (h16)hv[3];
        hbuf[(t & 1) ^ 1][r0 + 0][myu] = h0;
        hbuf[(t & 1) ^ 1][r0 + 1][myu] = h1;
        hbuf[(t & 1) ^ 1][r0 + 2][myu] = h2;
        hbuf[(t & 1) ^ 1][r0 + 3][myu] = h3;

        h16x2 p01; p01.x = h0; p01.y = h1;
        h16x2 p23; p23.x = h2; p23.y = h3;
        hp.x = __builtin_bit_cast(uint, p01);
        hp.y = __builtin_bit_cast(uint, p23);
        if (do_hout) *(uint2*)(hout + hob + (uint)t * hstep) = hp;

        __syncthreads();
    }

    *(f32x4*)(cstate + coff) = c;
    *(uint2*)(hstate + ((size_t)bt * KP + myu) * 16 + r0) = hp;
}

// ================= head =================
__global__ void k_head(const h16* __restrict__ h2s, const float* __restrict__ Wd,
                       const float* __restrict__ bd, float* __restrict__ out)
{
    __shared__ float lg[OUT_];
    const int b = blockIdx.x, j = threadIdx.x;
    const int bt = b >> 4, r = b & 15;
    if (j < OUT_) {
        float acc = bd[j];
        for (int u = 0; u < H2_; ++u)
            acc += (float)h2s[((size_t)bt * KP + u) * 16 + r] * Wd[u * OUT_ + j];
        lg[j] = acc;
    }
    __syncthreads();
    if (j < OUT_) {
        float m = -1e30f;
        for (int k = 0; k < OUT_; ++k) m = fmaxf(m, lg[k]);
        float s = 0.0f;
        for (int k = 0; k < OUT_; ++k) s += expf(lg[k] - m);
        out[b * OUT_ + j] = expf(lg[j] - m) / s;
    }
}

// ================= R9 fallback (known-good, 3.3 ms) =================
#define G1_  400
#define G2_  512
#define FBTC 32
#define FB_XP1  0
#define FB_XP2  0
#define FB_WQ   51200
#define FB_XS   134400
#define FB_W2Q  32768
#define FB_H1C  139264
#define FB_U2Q  32768
#define FB_ZBUF 160000
#define FB_H1PK 162048
#define FB_H2PK 162256
#define FB_H2F  162512
#define FB_LDS  163328

__device__ __forceinline__ float fd2(uint wv, uint hv, float cc) {
#if __has_builtin(__builtin_amdgcn_fdot2)
    return __builtin_amdgcn_fdot2(__builtin_bit_cast(h16x2, wv),
                                  __builtin_bit_cast(h16x2, hv), cc, false);
#else
    h16x2 a = __builtin_bit_cast(h16x2, wv), b = __builtin_bit_cast(h16x2, hv);
    return cc + (float)a.x * (float)b.x + (float)a.y * (float)b.y;
#endif
}

__device__ __forceinline__ void stage_quads(const float* __restrict__ P, const int G,
                                            const int NQ, const int KREAL,
                                            char* dst, const int j)
{
    if (j < G) {
        for (int q = 0; q < NQ; ++q) {
            float f[8];
            #pragma unroll
            for (int r = 0; r < 8; ++r) {
                const int k = 8 * q + r;
                f[r] = (k < KREAL) ? P[(size_t)k * G + j] : 0.0f;
            }
            uint4 u;
            u.x = pk2(f[0], f[1]); u.y = pk2(f[2], f[3]);
            u.z = pk2(f[4], f[5]); u.w = pk2(f[6], f[7]);
            *(uint4*)(dst + (size_t)(q * G + j) * 16) = u;
        }
    }
}

__global__ __launch_bounds__(512) void lstm_fallback(
    const float* __restrict__ x,
    const float* __restrict__ W1, const float* __restrict__ U1, const float* __restrict__ b1,
    const float* __restrict__ W2, const float* __restrict__ U2, const float* __restrict__ b2,
    const float* __restrict__ Wd, const float* __restrict__ bd,
    float* __restrict__ out)
{
    __shared__ uint4 smem4[FB_LDS / 16];
    char* sm = (char*)smem4;
    const int b = blockIdx.x;
    const int j = threadIdx.x;
    float c1 = 0.0f, c2 = 0.0f;

    const uint u2r0 = pk2(U2[120 * G2_ + j], U2[121 * G2_ + j]);
    const uint u2r1 = pk2(U2[122 * G2_ + j], U2[123 * G2_ + j]);
    const uint u2r2 = pk2(U2[124 * G2_ + j], U2[125 * G2_ + j]);
    const uint u2r3 = pk2(U2[126 * G2_ + j], U2[127 * G2_ + j]);

    if (j < 52) *(uint*)(sm + FB_H1PK + 4 * j) = 0u;
    if (j < 64) *(uint*)(sm + FB_H2PK + 4 * j) = 0u;
    __syncthreads();

    const float* xrow = x + (size_t)b * T_ * F_;
    for (int ch = 0; ch < T_ / FBTC; ++ch) {
        stage_quads(W1, G1_, 8, 64, sm + FB_WQ, j);
        #pragma unroll
        for (int r = 0; r < 2; ++r) {
            int v = r * 512 + j;
            float2 xv = *(const float2*)(xrow + ch * (FBTC * F_) + 2 * v);
            *(uint*)(sm + FB_XS + 4 * v) = pk2(xv.x, xv.y);
        }
        __syncthreads();
        if (j < G1_) {
            const float bj = b1[j];
            const uint4* WQ = (const uint4*)(sm + FB_WQ);
            for (int t = 0; t < FBTC; ++t) {
                const uint4* XQ = (const uint4*)(sm + FB_XS + t * 128);
                float a0 = bj, a1 = 0.f, a2 = 0.f, a3 = 0.f;
                #pragma unroll
                for (int q = 0; q < 8; ++q) {
                    uint4 wq = WQ[q * G1_ + j]; uint4 hq = XQ[q];
                    a0 = fd2(wq.x, hq.x, a0); a1 = fd2(wq.y, hq.y, a1);
                    a2 = fd2(wq.z, hq.z, a2); a3 = fd2(wq.w, hq.w, a3);
                }
                *(float*)(sm + FB_XP1 + 4 * (t * G1_ + j)) = (a0 + a1) + (a2 + a3);
            }
        }
        __syncthreads();
        stage_quads(U1, G1_, 13, H1_, sm + FB_WQ, j);
        __syncthreads();
        for (int t = 0; t < FBTC; ++t) {
            if (j < G1_) {
                const uint4* WQ = (const uint4*)(sm + FB_WQ);
                const uint4* HP = (const uint4*)(sm + FB_H1PK);
                float a0 = *(const float*)(sm + FB_XP1 + 4 * (t * G1_ + j));
                float a1 = 0.f, a2 = 0.f, a3 = 0.f;
                #pragma unroll
                for (int q = 0; q < 13; ++q) {
                    uint4 wq = WQ[q * G1_ + j]; uint4 hq = HP[q];
                    a0 = fd2(wq.x, hq.x, a0); a1 = fd2(wq.y, hq.y, a1);
                    a2 = fd2(wq.z, hq.z, a2); a3 = fd2(wq.w, hq.w, a3);
                }
                *(float*)(sm + FB_ZBUF + 4 * j) = (a0 + a1) + (a2 + a3);
            }
            __syncthreads();
            if (j < H1_) {
                const float* zb = (const float*)(sm + FB_ZBUF);
                float ig = sigm(zb[j]);
                float fg = sigm(zb[H1_ + j]);
                float gg = fmaxf(zb[2 * H1_ + j], 0.0f);
                float og = sigm(zb[3 * H1_ + j]);
                c1 = fg * c1 + ig * gg;
                float h = og * fmaxf(c1, 0.0f);
                h16 hh = (h16)h;
                *(h16*)(sm + FB_H1PK + 2 * j) = hh;
                *(h16*)(sm + FB_H1C + t * 208 + 2 * j) = hh;
            }
            __syncthreads();
        }
        stage_quads(W2, G2_, 13, H1_, sm + FB_W2Q, j);
        __syncthreads();
        {
            const float bj = b2[j];
            const uint4* WQ = (const uint4*)(sm + FB_W2Q);
            for (int t = 0; t < FBTC; ++t) {
                const uint4* HC = (const uint4*)(sm + FB_H1C + t * 208);
                float a0 = bj, a1 = 0.f, a2 = 0.f, a3 = 0.f;
                #pragma unroll
                for (int q = 0; q < 13; ++q) {
                    uint4 wq = WQ[q * G2_ + j]; uint4 hq = HC[q];
                    a0 = fd2(wq.x, hq.x, a0); a1 = fd2(wq.y, hq.y, a1);
                    a2 = fd2(wq.z, hq.z, a2); a3 = fd2(wq.w, hq.w, a3);
                }
                *(h16*)(sm + FB_XP2 + 2 * (t * G2_ + j)) = (h16)((a0 + a1) + (a2 + a3));
            }
        }
        __syncthreads();
        stage_quads(U2, G2_, 15, 120, sm + FB_U2Q, j);
        __syncthreads();
        for (int t = 0; t < FBTC; ++t) {
            {
                const uint4* WQ = (const uint4*)(sm + FB_U2Q);
                const uint4* HP = (const uint4*)(sm + FB_H2PK);
                float a0 = (float)*(const h16*)(sm + FB_XP2 + 2 * (t * G2_ + j));
                float a1 = 0.f, a2 = 0.f, a3 = 0.f;
                #pragma unroll
                for (int q = 0; q < 15; ++q) {
                    uint4 wq = WQ[q * G2_ + j]; uint4 hq = HP[q];
                    a0 = fd2(wq.x, hq.x, a0); a1 = fd2(wq.y, hq.y, a1);
                    a2 = fd2(wq.z, hq.z, a2); a3 = fd2(wq.w, hq.w, a3);
                }
                uint4 hp15 = ((const uint4*)(sm + FB_H2PK))[15];
                a0 = fd2(u2r0, hp15.x, a0); a1 = fd2(u2r1, hp15.y, a1);
                a2 = fd2(u2r2, hp15.z, a2); a3 = fd2(u2r3, hp15.w, a3);
                *(float*)(sm + FB_ZBUF + 4 * j) = (a0 + a1) + (a2 + a3);
            }
            __syncthreads();
            if (j < H2_) {
                const float* zb = (const float*)(sm + FB_ZBUF);
                float ig = sigm(zb[j]);
                float fg = sigm(zb[H2_ + j]);
                float gg = fmaxf(zb[2 * H2_ + j], 0.0f);
                float og = sigm(zb[3 * H2_ + j]);
                c2 = fg * c2 + ig * gg;
                float h = og * fmaxf(c2, 0.0f);
                *(h16*)(sm + FB_H2PK + 2 * j) = (h16)h;
                *(float*)(sm + FB_H2F + 4 * j) = h;
            }
            __syncthreads();
        }
    }
    if (j < OUT_) {
        const float* h2 = (const float*)(sm + FB_H2F);
        float acc = bd[j];
        #pragma unroll
        for (int k = 0; k < H2_; ++k) acc += h2[k] * Wd[k * OUT_ + j];
        *(float*)(sm + FB_ZBUF + 4 * j) = acc;
    }
    __syncthreads();
    if (j < OUT_) {
        const float* zb = (const float*)(sm + FB_ZBUF);
        float m = -1e30f;
        for (int k = 0; k < OUT_; ++k) m = fmaxf(m, zb[k]);
        float s = 0.0f;
        for (int k = 0; k < OUT_; ++k) s += expf(zb[k] - m);
        out[b * OUT_ + j] = expf(zb[j] - m) / s;
    }
}

// ================= launcher =================
extern "C" void kernel_launch(void* const* d_in, const int* in_sizes, int n_in,
                              void* d_out, int out_size, void* d_ws, size_t ws_size,
                              hipStream_t stream) {
    const float* x  = (const float*)d_in[0];
    const float* W1 = (const float*)d_in[1];
    const float* U1 = (const float*)d_in[2];
    const float* b1 = (const float*)d_in[3];
    const float* W2 = (const float*)d_in[4];
    const float* U2 = (const float*)d_in[5];
    const float* b2 = (const float*)d_in[6];
    const float* Wd = (const float*)d_in[7];
    const float* bd = (const float*)d_in[8];
    float* out = (float*)d_out;

    if (ws_size >= WS_NEED) {
        char* ws = (char*)d_ws;
        h16*   xp  = (h16*)(ws + OFF_XP);
        h16*   h1g = (h16*)(ws + OFF_H1G);
        float* c1  = (float*)(ws + OFF_C1);
        float* c2  = (float*)(ws + OFF_C2);
        h16*   h1s = (h16*)(ws + OFF_H1S);
        h16*   h2s = (h16*)(ws + OFF_H2S);
        for (int ch = 0; ch < NCH; ++ch) {
            k_dense<0><<<128, 512, 0, stream>>>(x, (const h16*)nullptr, W1, b1, H1_, ch, xp);
            k_rec<<<16, 512, 0, stream>>>(U1, H1_, xp, h1g, 1, c1, h1s, ch);
            k_dense<1><<<128, 512, 0, stream>>>((const float*)nullptr, h1g, W2, b2, H2_, ch, xp);
            k_rec<<<16, 512, 0, stream>>>(U2, H2_, xp, (h16*)nullptr, 0, c2, h2s, ch);
        }
        k_head<<<256, 64, 0, stream>>>(h2s, Wd, bd, out);
    } else {
        lstm_fallback<<<B_, 512, 0, stream>>>(x, W1, U1, b1, W2, U2, b2, Wd, bd, out);
    }
}